// Round 1
// baseline (384.669 us; speedup 1.0000x reference)
//
#include <hip/hip_runtime.h>

#define DIM 256
#define NA 16
#define NE 4
#define KTOT 288   // 16 atoms + 256 latent + 16 zero pad
#define KC 96      // K per third
#define PADR 104   // LDS row stride in elements (208 B, 16B-aligned, conflict-free)

typedef __attribute__((ext_vector_type(8))) short short8;
typedef __attribute__((ext_vector_type(4))) float f32x4;

static __device__ __forceinline__ ushort f2bf(float f) {
  union { float f; unsigned int u; } v; v.f = f;
  unsigned int r = (v.u + 0x7FFFu + ((v.u >> 16) & 1u)) >> 16;
  return (ushort)r;
}

// ---------------- prep 1: h = relu(latent@W1+b1)@W2+b2 ; build G = [atoms|h|0] bf16
__global__ __launch_bounds__(256) void prep_h_kernel(
    const float* __restrict__ latent, const float* __restrict__ atoms,
    const float* __restrict__ W1, const float* __restrict__ b1,
    const float* __restrict__ W2, const float* __restrict__ b2,
    float* __restrict__ h_out, ushort* __restrict__ G_out) {
  __shared__ float lat[16][DIM];
  __shared__ float t1[16][DIM];
  const int b = blockIdx.x >> 4, i0 = (blockIdx.x & 15) * 16;
  const int k = threadIdx.x;
  #pragma unroll
  for (int r = 0; r < 16; ++r) lat[r][k] = latent[(b*256 + i0 + r) * DIM + k];
  __syncthreads();
  float acc[16];
  #pragma unroll
  for (int r = 0; r < 16; ++r) acc[r] = b1[k];
  for (int c = 0; c < DIM; c += 4) {
    float w0 = W1[(c+0)*DIM + k], w1 = W1[(c+1)*DIM + k];
    float w2 = W1[(c+2)*DIM + k], w3 = W1[(c+3)*DIM + k];
    #pragma unroll
    for (int r = 0; r < 16; ++r) {
      const float4 l4 = *reinterpret_cast<const float4*>(&lat[r][c]);
      acc[r] += l4.x*w0 + l4.y*w1 + l4.z*w2 + l4.w*w3;
    }
  }
  #pragma unroll
  for (int r = 0; r < 16; ++r) t1[r][k] = fmaxf(acc[r], 0.f);
  __syncthreads();
  #pragma unroll
  for (int r = 0; r < 16; ++r) acc[r] = b2[k];
  for (int c = 0; c < DIM; c += 4) {
    float w0 = W2[(c+0)*DIM + k], w1 = W2[(c+1)*DIM + k];
    float w2 = W2[(c+2)*DIM + k], w3 = W2[(c+3)*DIM + k];
    #pragma unroll
    for (int r = 0; r < 16; ++r) {
      const float4 l4 = *reinterpret_cast<const float4*>(&t1[r][c]);
      acc[r] += l4.x*w0 + l4.y*w1 + l4.z*w2 + l4.w*w3;
    }
  }
  #pragma unroll
  for (int r = 0; r < 16; ++r) {
    int row = b*256 + i0 + r;
    h_out[row*DIM + k] = acc[r];
    G_out[row*KTOT + NA + k] = f2bf(acc[r]);
  }
  if (k < NA) {
    #pragma unroll
    for (int r = 0; r < 16; ++r) {
      int row = b*256 + i0 + r;
      G_out[row*KTOT + k] = f2bf(atoms[row*NA + k]);
      G_out[row*KTOT + 272 + k] = 0;
    }
  }
}

// ---------------- prep 2: W3T[k][c] = W3[1+c][k] (f32, zero-padded to 288)
__global__ __launch_bounds__(256) void prep_w3t_kernel(
    const float* __restrict__ W3, float* __restrict__ W3T) {
  const int kk = blockIdx.x, c = threadIdx.x;
  W3T[kk*KTOT + c] = (c < 272) ? W3[(1+c)*DIM + kk] : 0.f;
  if (c < 32) {
    int c2 = 256 + c;
    W3T[kk*KTOT + c2] = (c2 < 272) ? W3[(1+c2)*DIM + kk] : 0.f;
  }
}

// ---------------- main: per (b,i) workgroup, Z^T = (diag(g_i)W3')^T · G^T via MFMA
__global__ __launch_bounds__(512, 2) void edge_main_kernel(
    const float* __restrict__ positions, const float* __restrict__ atoms,
    const float* __restrict__ W3, const float* __restrict__ b3,
    const float* __restrict__ W4, const float* __restrict__ b4,
    const float* __restrict__ h_ws, const ushort* __restrict__ G,
    const float* __restrict__ W3T, float* __restrict__ out) {
  __shared__ union UU {
    struct { ushort A[256*PADR]; ushort BT[256*PADR]; } s;
    float partial[4][256][4];
  } u;
  __shared__ float g_lds[KTOT];
  __shared__ float dist_lds[256];

  const int b = blockIdx.x >> 8, i = blockIdx.x & 255;
  const int tid = threadIdx.x;
  const int lane = tid & 63, wave = tid >> 6;
  const int wn = wave & 3;        // n-quadrant: 64 cols of n each
  const int wj = wave >> 2;       // j-half: 128 rows of j each
  const int c15 = lane & 15, hi = lane >> 4;
  const int rowbase = b*256 + i;

  if (tid < KTOT)
    g_lds[tid] = (tid < NA) ? atoms[rowbase*NA + tid]
               : (tid < 272 ? h_ws[rowbase*DIM + (tid - NA)] : 0.f);
  if (tid < 256) {
    const float* pi = &positions[rowbase*3];
    const float* pj = &positions[(b*256 + tid)*3];
    float dx = pi[0]-pj[0], dy = pi[1]-pj[1], dz = pi[2]-pj[2];
    float d2 = dx*dx + dy*dy + dz*dz;
    dist_lds[tid] = d2 > 0.f ? sqrtf(d2) : 0.f;
  }

  f32x4 acc[4][8];
  #pragma unroll
  for (int nt = 0; nt < 4; ++nt)
    #pragma unroll
    for (int jt = 0; jt < 8; ++jt) { acc[nt][jt].x=0.f; acc[nt][jt].y=0.f; acc[nt][jt].z=0.f; acc[nt][jt].w=0.f; }

  const int bld_n = tid >> 1, bld_ch = (tid & 1) * 48;

  for (int t3 = 0; t3 < 3; ++t3) {
    __syncthreads();   // prev-iter MFMA done reading LDS (and init phase at t3==0)
    // ---- stage A third: G[b][j][t3*96 .. +96) -> u.s.A[j][0..96) (padded rows)
    uint4 tmp[6];
    #pragma unroll
    for (int q = 0; q < 6; ++q) {
      int id = q*512 + tid;
      int j = id / 12, cc = id % 12;
      tmp[q] = *reinterpret_cast<const uint4*>(&G[(b*256 + j)*KTOT + t3*KC + cc*8]);
    }
    #pragma unroll
    for (int q = 0; q < 6; ++q) {
      int id = q*512 + tid;
      int j = id / 12, cc = id % 12;
      *reinterpret_cast<uint4*>(&u.s.A[j*PADR + cc*8]) = tmp[q];
    }
    // ---- build BT[n][c] = g_i[c] * W3T[n][c]  (bf16)
    #pragma unroll
    for (int u8 = 0; u8 < 6; ++u8) {
      int c0 = bld_ch + u8*8;
      float4 wa = *reinterpret_cast<const float4*>(&W3T[bld_n*KTOT + t3*KC + c0]);
      float4 wb = *reinterpret_cast<const float4*>(&W3T[bld_n*KTOT + t3*KC + c0 + 4]);
      float4 ga = *reinterpret_cast<const float4*>(&g_lds[t3*KC + c0]);
      float4 gb = *reinterpret_cast<const float4*>(&g_lds[t3*KC + c0 + 4]);
      union { ushort us[8]; uint4 v; } pk;
      pk.us[0]=f2bf(wa.x*ga.x); pk.us[1]=f2bf(wa.y*ga.y); pk.us[2]=f2bf(wa.z*ga.z); pk.us[3]=f2bf(wa.w*ga.w);
      pk.us[4]=f2bf(wb.x*gb.x); pk.us[5]=f2bf(wb.y*gb.y); pk.us[6]=f2bf(wb.z*gb.z); pk.us[7]=f2bf(wb.w*gb.w);
      *reinterpret_cast<uint4*>(&u.s.BT[bld_n*PADR + c0]) = pk.v;
    }
    __syncthreads();
    // ---- MFMA: D = BT-frags (A-op) x A-frags (B-op)  => Z^T[n][j]
    #pragma unroll
    for (int kc = 0; kc < 3; ++kc) {
      short8 af[4], bfr[8];
      #pragma unroll
      for (int nt = 0; nt < 4; ++nt)
        af[nt] = *reinterpret_cast<const short8*>(&u.s.BT[(wn*64 + nt*16 + c15)*PADR + kc*32 + hi*8]);
      #pragma unroll
      for (int jt = 0; jt < 8; ++jt)
        bfr[jt] = *reinterpret_cast<const short8*>(&u.s.A[(wj*128 + jt*16 + c15)*PADR + kc*32 + hi*8]);
      #pragma unroll
      for (int nt = 0; nt < 4; ++nt)
        #pragma unroll
        for (int jt = 0; jt < 8; ++jt)
          acc[nt][jt] = __builtin_amdgcn_mfma_f32_16x16x32_bf16(af[nt], bfr[jt], acc[nt][jt], 0, 0, 0);
    }
  }
  __syncthreads();  // MFMA done; safe to overwrite union with partials

  // ---- epilogue: z = acc + dist*w30 + b3 ; relu ; second layer (256 -> 4)
  const int nb = wn*64 + hi*4;
  float b3v[4][4], w30v[4][4]; float4 w4v[4][4];
  #pragma unroll
  for (int nt = 0; nt < 4; ++nt)
    #pragma unroll
    for (int r = 0; r < 4; ++r) {
      int n = nb + nt*16 + r;
      b3v[nt][r]  = b3[n];
      w30v[nt][r] = W3[n];                 // W3 row 0 = dist weights
      w4v[nt][r]  = *reinterpret_cast<const float4*>(&W4[n*4]);
    }
  #pragma unroll
  for (int jt = 0; jt < 8; ++jt) {
    int j = wj*128 + jt*16 + c15;
    float d = dist_lds[j];
    float4 pe; pe.x=0.f; pe.y=0.f; pe.z=0.f; pe.w=0.f;
    #pragma unroll
    for (int nt = 0; nt < 4; ++nt)
      #pragma unroll
      for (int r = 0; r < 4; ++r) {
        float z  = acc[nt][jt][r] + d*w30v[nt][r] + b3v[nt][r];
        float rz = fmaxf(z, 0.f);
        pe.x += rz*w4v[nt][r].x; pe.y += rz*w4v[nt][r].y;
        pe.z += rz*w4v[nt][r].z; pe.w += rz*w4v[nt][r].w;
      }
    pe.x += __shfl_xor(pe.x, 16); pe.y += __shfl_xor(pe.y, 16);
    pe.z += __shfl_xor(pe.z, 16); pe.w += __shfl_xor(pe.w, 16);
    pe.x += __shfl_xor(pe.x, 32); pe.y += __shfl_xor(pe.y, 32);
    pe.z += __shfl_xor(pe.z, 32); pe.w += __shfl_xor(pe.w, 32);
    if (hi == 0) *reinterpret_cast<float4*>(&u.partial[wn][j][0]) = pe;
  }
  __syncthreads();
  #pragma unroll
  for (int rep = 0; rep < 2; ++rep) {
    int o = rep*512 + tid;
    int j = o >> 2, e = o & 3;
    float v = u.partial[0][j][e] + u.partial[1][j][e]
            + u.partial[2][j][e] + u.partial[3][j][e] + b4[e];
    out[(rowbase*256 + j)*NE + e] = v;
  }
}

extern "C" void kernel_launch(void* const* d_in, const int* in_sizes, int n_in,
                              void* d_out, int out_size, void* d_ws, size_t ws_size,
                              hipStream_t stream) {
  const float* latent    = (const float*)d_in[0];
  const float* positions = (const float*)d_in[1];
  const float* atoms     = (const float*)d_in[2];
  const float* W1 = (const float*)d_in[3];
  const float* b1 = (const float*)d_in[4];
  const float* W2 = (const float*)d_in[5];
  const float* b2 = (const float*)d_in[6];
  const float* W3 = (const float*)d_in[7];
  const float* b3 = (const float*)d_in[8];
  const float* W4 = (const float*)d_in[9];
  const float* b4 = (const float*)d_in[10];
  float* out = (float*)d_out;

  char* ws = (char*)d_ws;
  float*  h_ws   = (float*)ws;                          // 8*256*256*4   = 2,097,152 B
  ushort* G_ws   = (ushort*)(ws + 2097152);             // 8*256*288*2   = 1,179,648 B
  float*  W3T_ws = (float*)(ws + 2097152 + 1179648);    // 256*288*4     =   294,912 B

  hipLaunchKernelGGL(prep_h_kernel, dim3(128), dim3(256), 0, stream,
                     latent, atoms, W1, b1, W2, b2, h_ws, G_ws);
  hipLaunchKernelGGL(prep_w3t_kernel, dim3(256), dim3(256), 0, stream, W3, W3T_ws);
  hipLaunchKernelGGL(edge_main_kernel, dim3(2048), dim3(512), 0, stream,
                     positions, atoms, W3, b3, W4, b4, h_ws, G_ws, W3T_ws, out);
}

// Round 3
// 330.093 us; speedup vs baseline: 1.1653x; 1.1653x over previous
//
#include <hip/hip_runtime.h>

#define DIM 256
#define NA 16
#define NE 4
#define KTOT 288   // 16 atoms + 256 latent + 16 zero pad
#define KC 96      // K per third
#define ROWB 192   // LDS row bytes (96 bf16, no pad; XOR-swizzled)

typedef __attribute__((ext_vector_type(8))) short short8;
typedef __attribute__((ext_vector_type(4))) float f32x4;

static __device__ __forceinline__ ushort f2bf(float f) {
  union { float f; unsigned int u; } v; v.f = f;
  unsigned int r = (v.u + 0x7FFFu + ((v.u >> 16) & 1u)) >> 16;
  return (ushort)r;
}

static __device__ __forceinline__ unsigned cvtpk(float lo, float hi) {
  unsigned r;
  asm volatile("v_cvt_pk_bf16_f32 %0, %1, %2" : "=v"(r) : "v"(lo), "v"(hi));
  return r;
}

// XOR-swizzle a slab byte offset; row is the LDS row index (proven G4/m201 pattern)
static __device__ __forceinline__ int swz(int row, int byteoff) {
  return byteoff ^ ((row & 7) << 4);
}

// ---------------- prep 1: h = relu(latent@W1+b1)@W2+b2 ; build G = [atoms|h|0] bf16
__global__ __launch_bounds__(256) void prep_h_kernel(
    const float* __restrict__ latent, const float* __restrict__ atoms,
    const float* __restrict__ W1, const float* __restrict__ b1,
    const float* __restrict__ W2, const float* __restrict__ b2,
    float* __restrict__ h_out, ushort* __restrict__ G_out) {
  __shared__ float lat[16][DIM];
  __shared__ float t1[16][DIM];
  const int b = blockIdx.x >> 4, i0 = (blockIdx.x & 15) * 16;
  const int k = threadIdx.x;
  #pragma unroll
  for (int r = 0; r < 16; ++r) lat[r][k] = latent[(b*256 + i0 + r) * DIM + k];
  __syncthreads();
  float acc[16];
  #pragma unroll
  for (int r = 0; r < 16; ++r) acc[r] = b1[k];
  for (int c = 0; c < DIM; c += 4) {
    float w0 = W1[(c+0)*DIM + k], w1 = W1[(c+1)*DIM + k];
    float w2 = W1[(c+2)*DIM + k], w3 = W1[(c+3)*DIM + k];
    #pragma unroll
    for (int r = 0; r < 16; ++r) {
      const float4 l4 = *reinterpret_cast<const float4*>(&lat[r][c]);
      acc[r] += l4.x*w0 + l4.y*w1 + l4.z*w2 + l4.w*w3;
    }
  }
  #pragma unroll
  for (int r = 0; r < 16; ++r) t1[r][k] = fmaxf(acc[r], 0.f);
  __syncthreads();
  #pragma unroll
  for (int r = 0; r < 16; ++r) acc[r] = b2[k];
  for (int c = 0; c < DIM; c += 4) {
    float w0 = W2[(c+0)*DIM + k], w1 = W2[(c+1)*DIM + k];
    float w2 = W2[(c+2)*DIM + k], w3 = W2[(c+3)*DIM + k];
    #pragma unroll
    for (int r = 0; r < 16; ++r) {
      const float4 l4 = *reinterpret_cast<const float4*>(&t1[r][c]);
      acc[r] += l4.x*w0 + l4.y*w1 + l4.z*w2 + l4.w*w3;
    }
  }
  #pragma unroll
  for (int r = 0; r < 16; ++r) {
    int row = b*256 + i0 + r;
    h_out[row*DIM + k] = acc[r];
    G_out[row*KTOT + NA + k] = f2bf(acc[r]);
  }
  if (k < NA) {
    #pragma unroll
    for (int r = 0; r < 16; ++r) {
      int row = b*256 + i0 + r;
      G_out[row*KTOT + k] = f2bf(atoms[row*NA + k]);
      G_out[row*KTOT + 272 + k] = 0;
    }
  }
}

// ---------------- prep 2: W3T[k][c] = W3[1+c][k] (f32, zero-padded to 288)
__global__ __launch_bounds__(256) void prep_w3t_kernel(
    const float* __restrict__ W3, float* __restrict__ W3T) {
  const int kk = blockIdx.x, c = threadIdx.x;
  W3T[kk*KTOT + c] = (c < 272) ? W3[(1+c)*DIM + kk] : 0.f;
  if (c < 32) {
    int c2 = 256 + c;
    W3T[kk*KTOT + c2] = (c2 < 272) ? W3[(1+c2)*DIM + kk] : 0.f;
  }
}

// ---------------- main: per (b,i) workgroup, Z^T = (diag(g_i)W3')^T · G^T via MFMA
__global__ __launch_bounds__(512) void edge_main_kernel(
    const float* __restrict__ positions, const float* __restrict__ atoms,
    const float* __restrict__ W3, const float* __restrict__ b3,
    const float* __restrict__ W4, const float* __restrict__ b4,
    const float* __restrict__ h_ws, const ushort* __restrict__ G,
    const float* __restrict__ W3T, float* __restrict__ out) {
  __shared__ union UU {
    struct { char A[256*ROWB]; char BT[256*ROWB]; } s;   // 96 KB of bf16 slabs
    float partial[4][256][4];
  } u;
  __shared__ float g_lds[KTOT];
  __shared__ float dist_lds[256];

  const int b = blockIdx.x >> 8, i = blockIdx.x & 255;
  const int tid = threadIdx.x;
  const int lane = tid & 63, wave = tid >> 6;
  const int wn = wave & 3;        // n-quadrant: 64 cols of n each
  const int wj = wave >> 2;       // j-half: 128 rows of j each
  const int c15 = lane & 15, hi = lane >> 4;
  const int rowbase = b*256 + i;

  if (tid < KTOT)
    g_lds[tid] = (tid < NA) ? atoms[rowbase*NA + tid]
               : (tid < 272 ? h_ws[rowbase*DIM + (tid - NA)] : 0.f);
  if (tid < 256) {
    const float* pi = &positions[rowbase*3];
    const float* pj = &positions[(b*256 + tid)*3];
    float dx = pi[0]-pj[0], dy = pi[1]-pj[1], dz = pi[2]-pj[2];
    float d2 = dx*dx + dy*dy + dz*dz;
    dist_lds[tid] = d2 > 0.f ? sqrtf(d2) : 0.f;
  }

  f32x4 acc[4][8];
  #pragma unroll
  for (int nt = 0; nt < 4; ++nt)
    #pragma unroll
    for (int jt = 0; jt < 8; ++jt) { acc[nt][jt].x=0.f; acc[nt][jt].y=0.f; acc[nt][jt].z=0.f; acc[nt][jt].w=0.f; }

  const int bld_n = tid >> 1, bld_ch = (tid & 1) * 48;

  for (int t3 = 0; t3 < 3; ++t3) {
    __syncthreads();   // prev-iter MFMA done reading LDS (and init phase at t3==0)
    // ---- stage A third: G[b][j][t3*96 .. +96) -> A slab rows (swizzled)
    uint4 tmp[6];
    #pragma unroll
    for (int q = 0; q < 6; ++q) {
      int id = q*512 + tid;
      int j = id / 12, cc = id % 12;
      tmp[q] = *reinterpret_cast<const uint4*>(&G[(b*256 + j)*KTOT + t3*KC + cc*8]);
    }
    #pragma unroll
    for (int q = 0; q < 6; ++q) {
      int id = q*512 + tid;
      int j = id / 12, cc = id % 12;
      *reinterpret_cast<uint4*>(&u.s.A[swz(j, j*ROWB + cc*16)]) = tmp[q];
    }
    // ---- build BT[n][c] = g_i[c] * W3T[n][c]  (bf16, cvt_pk packed)
    #pragma unroll
    for (int u8 = 0; u8 < 6; ++u8) {
      int c0 = bld_ch + u8*8;
      float4 wa = *reinterpret_cast<const float4*>(&W3T[bld_n*KTOT + t3*KC + c0]);
      float4 wb = *reinterpret_cast<const float4*>(&W3T[bld_n*KTOT + t3*KC + c0 + 4]);
      float4 ga = *reinterpret_cast<const float4*>(&g_lds[t3*KC + c0]);
      float4 gb = *reinterpret_cast<const float4*>(&g_lds[t3*KC + c0 + 4]);
      uint4 pk;
      pk.x = cvtpk(wa.x*ga.x, wa.y*ga.y);
      pk.y = cvtpk(wa.z*ga.z, wa.w*ga.w);
      pk.z = cvtpk(wb.x*gb.x, wb.y*gb.y);
      pk.w = cvtpk(wb.z*gb.z, wb.w*gb.w);
      *reinterpret_cast<uint4*>(&u.s.BT[swz(bld_n, bld_n*ROWB + c0*2)]) = pk;
    }
    __syncthreads();
    // ---- MFMA: D = BT-frags (A-op) x A-frags (B-op)  => Z^T[n][j]
    #pragma unroll
    for (int kc = 0; kc < 3; ++kc) {
      short8 af[4], bfr[8];
      #pragma unroll
      for (int nt = 0; nt < 4; ++nt) {
        int r = wn*64 + nt*16 + c15;
        af[nt] = *reinterpret_cast<const short8*>(&u.s.BT[swz(r, r*ROWB + kc*64 + hi*16)]);
      }
      #pragma unroll
      for (int jt = 0; jt < 8; ++jt) {
        int r = wj*128 + jt*16 + c15;
        bfr[jt] = *reinterpret_cast<const short8*>(&u.s.A[swz(r, r*ROWB + kc*64 + hi*16)]);
      }
      #pragma unroll
      for (int nt = 0; nt < 4; ++nt)
        #pragma unroll
        for (int jt = 0; jt < 8; ++jt)
          acc[nt][jt] = __builtin_amdgcn_mfma_f32_16x16x32_bf16(af[nt], bfr[jt], acc[nt][jt], 0, 0, 0);
    }
  }
  __syncthreads();  // MFMA done; safe to overwrite union with partials

  // ---- epilogue: z = acc + dist*w30 + b3 ; relu ; second layer (256 -> 4)
  const int nb = wn*64 + hi*4;
  float b3v[4][4], w30v[4][4]; float4 w4v[4][4];
  #pragma unroll
  for (int nt = 0; nt < 4; ++nt)
    #pragma unroll
    for (int r = 0; r < 4; ++r) {
      int n = nb + nt*16 + r;
      b3v[nt][r]  = b3[n];
      w30v[nt][r] = W3[n];                 // W3 row 0 = dist weights
      w4v[nt][r]  = *reinterpret_cast<const float4*>(&W4[n*4]);
    }
  #pragma unroll
  for (int jt = 0; jt < 8; ++jt) {
    int j = wj*128 + jt*16 + c15;
    float d = dist_lds[j];
    float4 pe; pe.x=0.f; pe.y=0.f; pe.z=0.f; pe.w=0.f;
    #pragma unroll
    for (int nt = 0; nt < 4; ++nt)
      #pragma unroll
      for (int r = 0; r < 4; ++r) {
        float z  = acc[nt][jt][r] + d*w30v[nt][r] + b3v[nt][r];
        float rz = fmaxf(z, 0.f);
        pe.x += rz*w4v[nt][r].x; pe.y += rz*w4v[nt][r].y;
        pe.z += rz*w4v[nt][r].z; pe.w += rz*w4v[nt][r].w;
      }
    pe.x += __shfl_xor(pe.x, 16); pe.y += __shfl_xor(pe.y, 16);
    pe.z += __shfl_xor(pe.z, 16); pe.w += __shfl_xor(pe.w, 16);
    pe.x += __shfl_xor(pe.x, 32); pe.y += __shfl_xor(pe.y, 32);
    pe.z += __shfl_xor(pe.z, 32); pe.w += __shfl_xor(pe.w, 32);
    if (hi == 0) *reinterpret_cast<float4*>(&u.partial[wn][j][0]) = pe;
  }
  __syncthreads();
  #pragma unroll
  for (int rep = 0; rep < 2; ++rep) {
    int o = rep*512 + tid;
    int j = o >> 2, e = o & 3;
    float v = u.partial[0][j][e] + u.partial[1][j][e]
            + u.partial[2][j][e] + u.partial[3][j][e] + b4[e];
    out[(rowbase*256 + j)*NE + e] = v;
  }
}

extern "C" void kernel_launch(void* const* d_in, const int* in_sizes, int n_in,
                              void* d_out, int out_size, void* d_ws, size_t ws_size,
                              hipStream_t stream) {
  const float* latent    = (const float*)d_in[0];
  const float* positions = (const float*)d_in[1];
  const float* atoms     = (const float*)d_in[2];
  const float* W1 = (const float*)d_in[3];
  const float* b1 = (const float*)d_in[4];
  const float* W2 = (const float*)d_in[5];
  const float* b2 = (const float*)d_in[6];
  const float* W3 = (const float*)d_in[7];
  const float* b3 = (const float*)d_in[8];
  const float* W4 = (const float*)d_in[9];
  const float* b4 = (const float*)d_in[10];
  float* out = (float*)d_out;

  char* ws = (char*)d_ws;
  float*  h_ws   = (float*)ws;                          // 8*256*256*4   = 2,097,152 B
  ushort* G_ws   = (ushort*)(ws + 2097152);             // 8*256*288*2   = 1,179,648 B
  float*  W3T_ws = (float*)(ws + 2097152 + 1179648);    // 256*288*4     =   294,912 B

  hipLaunchKernelGGL(prep_h_kernel, dim3(128), dim3(256), 0, stream,
                     latent, atoms, W1, b1, W2, b2, h_ws, G_ws);
  hipLaunchKernelGGL(prep_w3t_kernel, dim3(256), dim3(256), 0, stream, W3, W3T_ws);
  hipLaunchKernelGGL(edge_main_kernel, dim3(2048), dim3(512), 0, stream,
                     positions, atoms, W3, b3, W4, b4, h_ws, G_ws, W3T_ws, out);
}

// Round 4
// 253.776 us; speedup vs baseline: 1.5158x; 1.3007x over previous
//
#include <hip/hip_runtime.h>

#define DIM 256
#define NA 16
#define NE 4
#define KTOT 288   // 16 atoms + 256 latent + 16 zero pad
#define KC 96      // K per third

typedef __attribute__((ext_vector_type(8))) short short8;
typedef __attribute__((ext_vector_type(4))) float f32x4;

static __device__ __forceinline__ ushort f2bf(float f) {
  union { float f; unsigned int u; } v; v.f = f;
  unsigned int r = (v.u + 0x7FFFu + ((v.u >> 16) & 1u)) >> 16;
  return (ushort)r;
}

static __device__ __forceinline__ unsigned cvtpk(float lo, float hi) {
  unsigned r;
  asm("v_cvt_pk_bf16_f32 %0, %1, %2" : "=v"(r) : "v"(lo), "v"(hi));
  return r;
}

// async global->LDS DMA, 16B per lane; lds dest must be wave-uniform (HW adds lane*16)
static __device__ __forceinline__ void gll16(const void* g, void* l) {
  __builtin_amdgcn_global_load_lds((const __attribute__((address_space(1))) void*)g,
                                   (__attribute__((address_space(3))) void*)l, 16, 0, 0);
}

// ---------------- prep 1: h = relu(latent@W1+b1)@W2+b2 ; build G = [atoms|h|0] bf16
__global__ __launch_bounds__(256) void prep_h_kernel(
    const float* __restrict__ latent, const float* __restrict__ atoms,
    const float* __restrict__ W1, const float* __restrict__ b1,
    const float* __restrict__ W2, const float* __restrict__ b2,
    float* __restrict__ h_out, ushort* __restrict__ G_out) {
  __shared__ float lat[16][DIM];
  __shared__ float t1[16][DIM];
  const int b = blockIdx.x >> 4, i0 = (blockIdx.x & 15) * 16;
  const int k = threadIdx.x;
  #pragma unroll
  for (int r = 0; r < 16; ++r) lat[r][k] = latent[(b*256 + i0 + r) * DIM + k];
  __syncthreads();
  float acc[16];
  #pragma unroll
  for (int r = 0; r < 16; ++r) acc[r] = b1[k];
  for (int c = 0; c < DIM; c += 4) {
    float w0 = W1[(c+0)*DIM + k], w1 = W1[(c+1)*DIM + k];
    float w2 = W1[(c+2)*DIM + k], w3 = W1[(c+3)*DIM + k];
    #pragma unroll
    for (int r = 0; r < 16; ++r) {
      const float4 l4 = *reinterpret_cast<const float4*>(&lat[r][c]);
      acc[r] += l4.x*w0 + l4.y*w1 + l4.z*w2 + l4.w*w3;
    }
  }
  #pragma unroll
  for (int r = 0; r < 16; ++r) t1[r][k] = fmaxf(acc[r], 0.f);
  __syncthreads();
  #pragma unroll
  for (int r = 0; r < 16; ++r) acc[r] = b2[k];
  for (int c = 0; c < DIM; c += 4) {
    float w0 = W2[(c+0)*DIM + k], w1 = W2[(c+1)*DIM + k];
    float w2 = W2[(c+2)*DIM + k], w3 = W2[(c+3)*DIM + k];
    #pragma unroll
    for (int r = 0; r < 16; ++r) {
      const float4 l4 = *reinterpret_cast<const float4*>(&t1[r][c]);
      acc[r] += l4.x*w0 + l4.y*w1 + l4.z*w2 + l4.w*w3;
    }
  }
  #pragma unroll
  for (int r = 0; r < 16; ++r) {
    int row = b*256 + i0 + r;
    h_out[row*DIM + k] = acc[r];
    G_out[row*KTOT + NA + k] = f2bf(acc[r]);
  }
  if (k < NA) {
    #pragma unroll
    for (int r = 0; r < 16; ++r) {
      int row = b*256 + i0 + r;
      G_out[row*KTOT + k] = f2bf(atoms[row*NA + k]);
      G_out[row*KTOT + 272 + k] = 0;
    }
  }
}

// ---------------- prep 2: W3T[k][c] = W3[1+c][k] (f32, zero-padded to 288)
__global__ __launch_bounds__(256) void prep_w3t_kernel(
    const float* __restrict__ W3, float* __restrict__ W3T) {
  const int kk = blockIdx.x, c = threadIdx.x;
  W3T[kk*KTOT + c] = (c < 272) ? W3[(1+c)*DIM + kk] : 0.f;
  if (c < 32) {
    int c2 = 256 + c;
    W3T[kk*KTOT + c2] = (c2 < 272) ? W3[(1+c2)*DIM + kk] : 0.f;
  }
}

// ---------------- main: per (b,i) workgroup
// Z^T[n][j] = sum_c (g_i[c]*W3T[n][c]) * G[j][c]  via MFMA; af in registers.
// LDS A-slab tiled-linear: offset16(rb,ks,c15) = (rb*12+ks)*16 + c15 -> every
// wave op is uniform_base + lane*16 (conflict-free by construction).
__global__ __launch_bounds__(512) void edge_main_kernel(
    const float* __restrict__ positions, const float* __restrict__ atoms,
    const float* __restrict__ W3, const float* __restrict__ b3,
    const float* __restrict__ W4, const float* __restrict__ b4,
    const float* __restrict__ h_ws, const ushort* __restrict__ G,
    const float* __restrict__ W3T, float* __restrict__ out) {
  __shared__ union UU {
    char bufs[2][49152];          // double-buffered A slab (48KB each)
    float partial[8][256][4];     // epilogue partials (32KB), used after final barrier
  } u;
  __shared__ float g_lds[KTOT];
  __shared__ float dist_lds[256];

  const int b = blockIdx.x >> 8, i = blockIdx.x & 255;
  const int tid = threadIdx.x;
  const int lane = tid & 63, w = tid >> 6;     // w = n-group (8 groups of 32)
  const int c15 = lane & 15, hi = lane >> 4;
  const int rowbase = b*256 + i;

  if (tid < KTOT)
    g_lds[tid] = (tid < NA) ? atoms[rowbase*NA + tid]
               : (tid < 272 ? h_ws[rowbase*DIM + (tid - NA)] : 0.f);
  if (tid < 256) {
    const float* pi = &positions[rowbase*3];
    const float* pj = &positions[(b*256 + tid)*3];
    float dx = pi[0]-pj[0], dy = pi[1]-pj[1], dz = pi[2]-pj[2];
    float d2 = dx*dx + dy*dy + dz*dz;
    dist_lds[tid] = d2 > 0.f ? sqrtf(d2) : 0.f;
  }

  // ---- async stage of one K-third into bufs[bufi] (6 x 16B DMA per lane)
  auto stage = [&](int bufi, int t3) {
    char* base = &u.bufs[bufi][w * 6144];
    #pragma unroll
    for (int ch = 0; ch < 6; ++ch) {
      int st = w*24 + ch*4 + hi;            // subtile index (rb*12 + ks)
      int rb = st / 12, ks = st - rb*12;
      const ushort* src = &G[(size_t)(b*256 + rb*16 + c15) * KTOT + t3*KC + ks*8];
      gll16(src, base + ch*1024);           // uniform dest; lane data at +lane*16
    }
  };

  f32x4 acc[2][16];
  #pragma unroll
  for (int nt = 0; nt < 2; ++nt)
    #pragma unroll
    for (int jt = 0; jt < 16; ++jt) { acc[nt][jt].x=0.f; acc[nt][jt].y=0.f; acc[nt][jt].z=0.f; acc[nt][jt].w=0.f; }

  stage(0, 0);
  __syncthreads();   // g_lds/dist ready + stage(0) DMA drained (vmcnt0 in barrier)

  #pragma unroll
  for (int t3 = 0; t3 < 3; ++t3) {
    // ---- build af[kc][nt] in registers: bf16(g[c] * W3T[n][c]); n = w*32+nt*16+c15
    float4 gq[6];
    #pragma unroll
    for (int kc2 = 0; kc2 < 3; ++kc2) {
      gq[kc2*2+0] = *reinterpret_cast<const float4*>(&g_lds[t3*KC + kc2*32 + hi*8]);
      gq[kc2*2+1] = *reinterpret_cast<const float4*>(&g_lds[t3*KC + kc2*32 + hi*8 + 4]);
    }
    short8 af[3][2];
    #pragma unroll
    for (int nt = 0; nt < 2; ++nt) {
      int n = w*32 + nt*16 + c15;
      const float* wp = &W3T[(size_t)n*KTOT + t3*KC + hi*8];
      #pragma unroll
      for (int kc2 = 0; kc2 < 3; ++kc2) {
        float4 wa = *reinterpret_cast<const float4*>(&wp[kc2*32]);
        float4 wb = *reinterpret_cast<const float4*>(&wp[kc2*32 + 4]);
        float4 ga = gq[kc2*2], gb = gq[kc2*2+1];
        union { unsigned uu[4]; short8 s8; } pk;
        pk.uu[0] = cvtpk(wa.x*ga.x, wa.y*ga.y);
        pk.uu[1] = cvtpk(wa.z*ga.z, wa.w*ga.w);
        pk.uu[2] = cvtpk(wb.x*gb.x, wb.y*gb.y);
        pk.uu[3] = cvtpk(wb.z*gb.z, wb.w*gb.w);
        af[kc2][nt] = pk.s8;
      }
    }
    __syncthreads();                 // all waves' stage(t3) landed; prev MFMA reads done
    if (t3 < 2) stage((t3 + 1) & 1, t3 + 1);   // prefetch next third into other buffer
    // ---- MFMA over this third: 48 contiguous 1KB ds_reads + 96 MFMA per wave
    const char* bp = u.bufs[t3 & 1];
    #pragma unroll
    for (int kc2 = 0; kc2 < 3; ++kc2) {
      #pragma unroll
      for (int jt = 0; jt < 16; ++jt) {
        short8 bb = *reinterpret_cast<const short8*>(bp + (jt*12 + kc2*4)*256 + lane*16);
        acc[0][jt] = __builtin_amdgcn_mfma_f32_16x16x32_bf16(af[kc2][0], bb, acc[0][jt], 0, 0, 0);
        acc[1][jt] = __builtin_amdgcn_mfma_f32_16x16x32_bf16(af[kc2][1], bb, acc[1][jt], 0, 0, 0);
      }
    }
  }
  __syncthreads();   // MFMA done; safe to overwrite union with partials

  // ---- epilogue: z = acc + dist*w30 + b3 ; relu ; second layer (256 -> 4)
  float b3v[2][4], w30v[2][4]; float4 w4v[2][4];
  #pragma unroll
  for (int nt = 0; nt < 2; ++nt)
    #pragma unroll
    for (int r = 0; r < 4; ++r) {
      int n = w*32 + nt*16 + hi*4 + r;
      b3v[nt][r]  = b3[n];
      w30v[nt][r] = W3[n];                 // W3 row 0 = dist weights
      w4v[nt][r]  = *reinterpret_cast<const float4*>(&W4[n*4]);
    }
  #pragma unroll
  for (int jt = 0; jt < 16; ++jt) {
    int j = jt*16 + c15;
    float d = dist_lds[j];
    float4 pe; pe.x=0.f; pe.y=0.f; pe.z=0.f; pe.w=0.f;
    #pragma unroll
    for (int nt = 0; nt < 2; ++nt)
      #pragma unroll
      for (int r = 0; r < 4; ++r) {
        float z  = acc[nt][jt][r] + d*w30v[nt][r] + b3v[nt][r];
        float rz = fmaxf(z, 0.f);
        pe.x += rz*w4v[nt][r].x; pe.y += rz*w4v[nt][r].y;
        pe.z += rz*w4v[nt][r].z; pe.w += rz*w4v[nt][r].w;
      }
    pe.x += __shfl_xor(pe.x, 16); pe.y += __shfl_xor(pe.y, 16);
    pe.z += __shfl_xor(pe.z, 16); pe.w += __shfl_xor(pe.w, 16);
    pe.x += __shfl_xor(pe.x, 32); pe.y += __shfl_xor(pe.y, 32);
    pe.z += __shfl_xor(pe.z, 32); pe.w += __shfl_xor(pe.w, 32);
    if (hi == 0) *reinterpret_cast<float4*>(&u.partial[w][j][0]) = pe;
  }
  __syncthreads();
  #pragma unroll
  for (int rep = 0; rep < 2; ++rep) {
    int o = rep*512 + tid;
    int j = o >> 2, e = o & 3;
    float v = u.partial[0][j][e] + u.partial[1][j][e]
            + u.partial[2][j][e] + u.partial[3][j][e]
            + u.partial[4][j][e] + u.partial[5][j][e]
            + u.partial[6][j][e] + u.partial[7][j][e] + b4[e];
    out[(rowbase*256 + j)*NE + e] = v;
  }
}

extern "C" void kernel_launch(void* const* d_in, const int* in_sizes, int n_in,
                              void* d_out, int out_size, void* d_ws, size_t ws_size,
                              hipStream_t stream) {
  const float* latent    = (const float*)d_in[0];
  const float* positions = (const float*)d_in[1];
  const float* atoms     = (const float*)d_in[2];
  const float* W1 = (const float*)d_in[3];
  const float* b1 = (const float*)d_in[4];
  const float* W2 = (const float*)d_in[5];
  const float* b2 = (const float*)d_in[6];
  const float* W3 = (const float*)d_in[7];
  const float* b3 = (const float*)d_in[8];
  const float* W4 = (const float*)d_in[9];
  const float* b4 = (const float*)d_in[10];
  float* out = (float*)d_out;

  char* ws = (char*)d_ws;
  float*  h_ws   = (float*)ws;                          // 8*256*256*4   = 2,097,152 B
  ushort* G_ws   = (ushort*)(ws + 2097152);             // 8*256*288*2   = 1,179,648 B
  float*  W3T_ws = (float*)(ws + 2097152 + 1179648);    // 256*288*4     =   294,912 B

  hipLaunchKernelGGL(prep_h_kernel, dim3(128), dim3(256), 0, stream,
                     latent, atoms, W1, b1, W2, b2, h_ws, G_ws);
  hipLaunchKernelGGL(prep_w3t_kernel, dim3(256), dim3(256), 0, stream, W3, W3T_ws);
  hipLaunchKernelGGL(edge_main_kernel, dim3(2048), dim3(512), 0, stream,
                     positions, atoms, W3, b3, W4, b4, h_ws, G_ws, W3T_ws, out);
}

// Round 5
// 153.011 us; speedup vs baseline: 2.5140x; 1.6585x over previous
//
#include <hip/hip_runtime.h>

#define DIM 256
#define NA 16
#define NE 4
#define KTOT 288   // 16 atoms + 256 latent + 16 zero pad
#define KC 96      // K per third

typedef __attribute__((ext_vector_type(8))) short short8;
typedef __attribute__((ext_vector_type(4))) float f32x4;

static __device__ __forceinline__ ushort f2bf(float f) {
  union { float f; unsigned int u; } v; v.f = f;
  unsigned int r = (v.u + 0x7FFFu + ((v.u >> 16) & 1u)) >> 16;
  return (ushort)r;
}

static __device__ __forceinline__ float bf2f(ushort s) {
  union { unsigned int u; float f; } v; v.u = ((unsigned int)s) << 16;
  return v.f;
}

static __device__ __forceinline__ unsigned cvtpk(float lo, float hi) {
  unsigned r;
  asm("v_cvt_pk_bf16_f32 %0, %1, %2" : "=v"(r) : "v"(lo), "v"(hi));
  return r;
}

// async global->LDS DMA, 16B per lane; lds dest must be wave-uniform (HW adds lane*16)
static __device__ __forceinline__ void gll16(const void* g, void* l) {
  __builtin_amdgcn_global_load_lds((const __attribute__((address_space(1))) void*)g,
                                   (__attribute__((address_space(3))) void*)l, 16, 0, 0);
}

// ---------------- prep 1: h = relu(latent@W1+b1)@W2+b2 ; build G = [atoms|h|0] bf16
// 256 WGs x 256 thr, 8 rows each (1 WG/CU)
__global__ __launch_bounds__(256) void prep_h_kernel(
    const float* __restrict__ latent, const float* __restrict__ atoms,
    const float* __restrict__ W1, const float* __restrict__ b1,
    const float* __restrict__ W2, const float* __restrict__ b2,
    float* __restrict__ h_out, ushort* __restrict__ G_out) {
  __shared__ float lat[8][DIM];
  __shared__ float t1[8][DIM];
  const int b = blockIdx.x >> 5, i0 = (blockIdx.x & 31) * 8;
  const int k = threadIdx.x;
  #pragma unroll
  for (int r = 0; r < 8; ++r) lat[r][k] = latent[(b*256 + i0 + r) * DIM + k];
  __syncthreads();
  float acc[8];
  #pragma unroll
  for (int r = 0; r < 8; ++r) acc[r] = b1[k];
  for (int c = 0; c < DIM; c += 4) {
    float w0 = W1[(c+0)*DIM + k], w1 = W1[(c+1)*DIM + k];
    float w2 = W1[(c+2)*DIM + k], w3 = W1[(c+3)*DIM + k];
    #pragma unroll
    for (int r = 0; r < 8; ++r) {
      const float4 l4 = *reinterpret_cast<const float4*>(&lat[r][c]);
      acc[r] += l4.x*w0 + l4.y*w1 + l4.z*w2 + l4.w*w3;
    }
  }
  #pragma unroll
  for (int r = 0; r < 8; ++r) t1[r][k] = fmaxf(acc[r], 0.f);
  __syncthreads();
  #pragma unroll
  for (int r = 0; r < 8; ++r) acc[r] = b2[k];
  for (int c = 0; c < DIM; c += 4) {
    float w0 = W2[(c+0)*DIM + k], w1 = W2[(c+1)*DIM + k];
    float w2 = W2[(c+2)*DIM + k], w3 = W2[(c+3)*DIM + k];
    #pragma unroll
    for (int r = 0; r < 8; ++r) {
      const float4 l4 = *reinterpret_cast<const float4*>(&t1[r][c]);
      acc[r] += l4.x*w0 + l4.y*w1 + l4.z*w2 + l4.w*w3;
    }
  }
  #pragma unroll
  for (int r = 0; r < 8; ++r) {
    int row = b*256 + i0 + r;
    h_out[row*DIM + k] = acc[r];
    G_out[row*KTOT + NA + k] = f2bf(acc[r]);
  }
  if (k < NA) {
    #pragma unroll
    for (int r = 0; r < 8; ++r) {
      int row = b*256 + i0 + r;
      G_out[row*KTOT + k] = f2bf(atoms[row*NA + k]);
      G_out[row*KTOT + 272 + k] = 0;
    }
  }
}

// ---------------- prep 2: W3T[k][c] = bf16(W3[1+c][k]) zero-padded to 288
__global__ __launch_bounds__(256) void prep_w3t_kernel(
    const float* __restrict__ W3, ushort* __restrict__ W3T) {
  const int kk = blockIdx.x, c = threadIdx.x;
  W3T[kk*KTOT + c] = (c < 272) ? f2bf(W3[(1+c)*DIM + kk]) : (ushort)0;
  if (c < 32) {
    int c2 = 256 + c;
    W3T[kk*KTOT + c2] = (c2 < 272) ? f2bf(W3[(1+c2)*DIM + kk]) : (ushort)0;
  }
}

// ---------------- main: per (b,i) workgroup
// Z^T[n][j] = sum_c (g_i[c]*W3T[n][c]) * G[j][c]  via MFMA; af in registers.
// LDS A-slab tiled-linear: every wave op is uniform_base + lane*16 (conflict-free).
__global__ __attribute__((amdgpu_flat_work_group_size(512,512), amdgpu_waves_per_eu(2,2)))
void edge_main_kernel(
    const float* __restrict__ positions, const float* __restrict__ atoms,
    const float* __restrict__ W3, const float* __restrict__ b3,
    const float* __restrict__ W4, const float* __restrict__ b4,
    const float* __restrict__ h_ws, const ushort* __restrict__ G,
    const ushort* __restrict__ W3T, float* __restrict__ out) {
  __shared__ union UU {
    char bufs[2][49152];          // double-buffered A slab (48KB each)
    float partial[8][256][4];     // epilogue partials (32KB), used after final barrier
  } u;
  __shared__ float g_lds[KTOT];
  __shared__ float dist_lds[256];

  const int b = blockIdx.x >> 8, i = blockIdx.x & 255;
  const int tid = threadIdx.x;
  const int lane = tid & 63, w = tid >> 6;     // w = n-group (8 groups of 32)
  const int c15 = lane & 15, hi = lane >> 4;
  const int rowbase = b*256 + i;

  if (tid < KTOT)
    g_lds[tid] = (tid < NA) ? atoms[rowbase*NA + tid]
               : (tid < 272 ? h_ws[rowbase*DIM + (tid - NA)] : 0.f);
  if (tid < 256) {
    const float* pi = &positions[rowbase*3];
    const float* pj = &positions[(b*256 + tid)*3];
    float dx = pi[0]-pj[0], dy = pi[1]-pj[1], dz = pi[2]-pj[2];
    float d2 = dx*dx + dy*dy + dz*dz;
    dist_lds[tid] = d2 > 0.f ? sqrtf(d2) : 0.f;
  }

  // ---- async stage of one K-third into bufs[bufi] (6 x 16B DMA per lane)
  auto stage = [&](int bufi, int t3) {
    char* base = &u.bufs[bufi][w * 6144];
    #pragma unroll
    for (int ch = 0; ch < 6; ++ch) {
      int st = w*24 + ch*4 + hi;            // subtile index (rb*12 + ks)
      int rb = st / 12, ks = st - rb*12;
      const ushort* src = &G[(size_t)(b*256 + rb*16 + c15) * KTOT + t3*KC + ks*8];
      gll16(src, base + ch*1024);           // uniform dest; lane data at +lane*16
    }
  };

  f32x4 acc[2][16];
  #pragma unroll
  for (int nt = 0; nt < 2; ++nt)
    #pragma unroll
    for (int jt = 0; jt < 16; ++jt) { acc[nt][jt].x=0.f; acc[nt][jt].y=0.f; acc[nt][jt].z=0.f; acc[nt][jt].w=0.f; }

  stage(0, 0);
  __syncthreads();   // g_lds/dist ready + stage(0) DMA drained (vmcnt0 in barrier)

  #pragma unroll
  for (int t3 = 0; t3 < 3; ++t3) {
    // ---- build af[kc][nt] in registers: bf16(g[c] * W3T[n][c]); n = w*32+nt*16+c15
    float4 gq[6];
    #pragma unroll
    for (int kc2 = 0; kc2 < 3; ++kc2) {
      gq[kc2*2+0] = *reinterpret_cast<const float4*>(&g_lds[t3*KC + kc2*32 + hi*8]);
      gq[kc2*2+1] = *reinterpret_cast<const float4*>(&g_lds[t3*KC + kc2*32 + hi*8 + 4]);
    }
    short8 af[3][2];
    #pragma unroll
    for (int nt = 0; nt < 2; ++nt) {
      int n = w*32 + nt*16 + c15;
      const ushort* wp = &W3T[(size_t)n*KTOT + t3*KC + hi*8];
      #pragma unroll
      for (int kc2 = 0; kc2 < 3; ++kc2) {
        union { ushort us[8]; short8 s8; } wv;
        wv.s8 = *reinterpret_cast<const short8*>(&wp[kc2*32]);
        float4 ga = gq[kc2*2], gb = gq[kc2*2+1];
        union { unsigned uu[4]; short8 s8; } pk;
        pk.uu[0] = cvtpk(bf2f(wv.us[0])*ga.x, bf2f(wv.us[1])*ga.y);
        pk.uu[1] = cvtpk(bf2f(wv.us[2])*ga.z, bf2f(wv.us[3])*ga.w);
        pk.uu[2] = cvtpk(bf2f(wv.us[4])*gb.x, bf2f(wv.us[5])*gb.y);
        pk.uu[3] = cvtpk(bf2f(wv.us[6])*gb.z, bf2f(wv.us[7])*gb.w);
        af[kc2][nt] = pk.s8;
      }
    }
    __syncthreads();                 // all waves' stage(t3) landed; prev MFMA reads done
    if (t3 < 2) stage((t3 + 1) & 1, t3 + 1);   // prefetch next third into other buffer
    // ---- MFMA over this third: 48 contiguous 1KB ds_reads + 96 MFMA per wave
    const char* bp = u.bufs[t3 & 1];
    #pragma unroll
    for (int kc2 = 0; kc2 < 3; ++kc2) {
      #pragma unroll
      for (int jt = 0; jt < 16; ++jt) {
        short8 bb = *reinterpret_cast<const short8*>(bp + (jt*12 + kc2*4)*256 + lane*16);
        acc[0][jt] = __builtin_amdgcn_mfma_f32_16x16x32_bf16(af[kc2][0], bb, acc[0][jt], 0, 0, 0);
        acc[1][jt] = __builtin_amdgcn_mfma_f32_16x16x32_bf16(af[kc2][1], bb, acc[1][jt], 0, 0, 0);
      }
    }
  }
  __syncthreads();   // MFMA done; safe to overwrite union with partials

  // ---- epilogue: z = acc + dist*w30 + b3 ; relu ; second layer (256 -> 4)
  float b3v[2][4], w30v[2][4]; float4 w4v[2][4];
  #pragma unroll
  for (int nt = 0; nt < 2; ++nt)
    #pragma unroll
    for (int r = 0; r < 4; ++r) {
      int n = w*32 + nt*16 + hi*4 + r;
      b3v[nt][r]  = b3[n];
      w30v[nt][r] = W3[n];                 // W3 row 0 = dist weights
      w4v[nt][r]  = *reinterpret_cast<const float4*>(&W4[n*4]);
    }
  #pragma unroll
  for (int jt = 0; jt < 16; ++jt) {
    int j = jt*16 + c15;
    float d = dist_lds[j];
    float4 pe; pe.x=0.f; pe.y=0.f; pe.z=0.f; pe.w=0.f;
    #pragma unroll
    for (int nt = 0; nt < 2; ++nt)
      #pragma unroll
      for (int r = 0; r < 4; ++r) {
        float z  = acc[nt][jt][r] + d*w30v[nt][r] + b3v[nt][r];
        float rz = fmaxf(z, 0.f);
        pe.x += rz*w4v[nt][r].x; pe.y += rz*w4v[nt][r].y;
        pe.z += rz*w4v[nt][r].z; pe.w += rz*w4v[nt][r].w;
      }
    pe.x += __shfl_xor(pe.x, 16); pe.y += __shfl_xor(pe.y, 16);
    pe.z += __shfl_xor(pe.z, 16); pe.w += __shfl_xor(pe.w, 16);
    pe.x += __shfl_xor(pe.x, 32); pe.y += __shfl_xor(pe.y, 32);
    pe.z += __shfl_xor(pe.z, 32); pe.w += __shfl_xor(pe.w, 32);
    if (hi == 0) *reinterpret_cast<float4*>(&u.partial[w][j][0]) = pe;
  }
  __syncthreads();
  #pragma unroll
  for (int rep = 0; rep < 2; ++rep) {
    int o = rep*512 + tid;
    int j = o >> 2, e = o & 3;
    float v = u.partial[0][j][e] + u.partial[1][j][e]
            + u.partial[2][j][e] + u.partial[3][j][e]
            + u.partial[4][j][e] + u.partial[5][j][e]
            + u.partial[6][j][e] + u.partial[7][j][e] + b4[e];
    out[(rowbase*256 + j)*NE + e] = v;
  }
}

extern "C" void kernel_launch(void* const* d_in, const int* in_sizes, int n_in,
                              void* d_out, int out_size, void* d_ws, size_t ws_size,
                              hipStream_t stream) {
  const float* latent    = (const float*)d_in[0];
  const float* positions = (const float*)d_in[1];
  const float* atoms     = (const float*)d_in[2];
  const float* W1 = (const float*)d_in[3];
  const float* b1 = (const float*)d_in[4];
  const float* W2 = (const float*)d_in[5];
  const float* b2 = (const float*)d_in[6];
  const float* W3 = (const float*)d_in[7];
  const float* b3 = (const float*)d_in[8];
  const float* W4 = (const float*)d_in[9];
  const float* b4 = (const float*)d_in[10];
  float* out = (float*)d_out;

  char* ws = (char*)d_ws;
  float*  h_ws   = (float*)ws;                          // 8*256*256*4   = 2,097,152 B
  ushort* G_ws   = (ushort*)(ws + 2097152);             // 8*256*288*2   = 1,179,648 B
  ushort* W3T_ws = (ushort*)(ws + 2097152 + 1179648);   // 256*288*2     =   147,456 B

  hipLaunchKernelGGL(prep_h_kernel, dim3(256), dim3(256), 0, stream,
                     latent, atoms, W1, b1, W2, b2, h_ws, G_ws);
  hipLaunchKernelGGL(prep_w3t_kernel, dim3(256), dim3(256), 0, stream, W3, W3T_ws);
  hipLaunchKernelGGL(edge_main_kernel, dim3(2048), dim3(512), 0, stream,
                     positions, atoms, W3, b3, W4, b4, h_ws, G_ws, W3T_ws, out);
}